// Round 6
// baseline (6030.528 us; speedup 1.0000x reference)
//
#include <hip/hip_runtime.h>

#define IN_DIM 32
#define HID 64
#define LN_EPS 1e-5f

typedef unsigned short ush;
typedef unsigned int u32;
typedef __attribute__((ext_vector_type(8))) short bf16x8;
typedef __attribute__((ext_vector_type(4))) float f32x4;

static __device__ __forceinline__ ush f2b(float f) {
    union { float f; unsigned int i; } v; v.f = f;
    unsigned int x = v.i;
    return (ush)((x + 0x7fffu + ((x >> 16) & 1u)) >> 16);  // RNE
}

__global__ __launch_bounds__(256) void zero_i32(int* __restrict__ p, int n) {
    const int i = blockIdx.x * 256 + threadIdx.x;
    if (i < n) p[i] = 0;
}

__global__ __launch_bounds__(256) void zero16(uint4* __restrict__ p, int n16) {
    const int i = blockIdx.x * 256 + threadIdx.x;
    if (i < n16) p[i] = make_uint4(0u, 0u, 0u, 0u);
}

static __device__ __forceinline__ bool sniff_idx64(const int* idx) {
    int zc = 0;
    #pragma unroll
    for (int t = 0; t < 8; ++t) zc += (idx[2 * t + 1] == 0) ? 1 : 0;
    return zc >= 7;
}

// ---- bucket pipeline: bucket = node >> 7 (128 nodes/bucket) ----

__global__ __launch_bounds__(256) void bucket_count(
    const int* __restrict__ idx, int* __restrict__ bcnt, int E, int N)
{
    const bool idx64 = sniff_idx64(idx);
    const int i = blockIdx.x * 256 + threadIdx.x;   // endpoint slot < 2E
    if (i >= 2 * E) return;
    int node = idx64 ? idx[2 * (size_t)i] : idx[i];
    node = min(max(node, 0), N - 1);
    atomicAdd(&bcnt[node >> 7], 1);
}

// in-place exclusive scan, single block (n <= ~100k)
__global__ __launch_bounds__(1024) void scan_excl(int* __restrict__ a, int n) {
    __shared__ int lds[1024];
    const int t = threadIdx.x;
    const int L = (n + 1023) >> 10;
    const int lo = t * L, hi = min(n, lo + L);
    int s = 0;
    for (int i = lo; i < hi; ++i) s += a[i];
    lds[t] = s;
    __syncthreads();
    #pragma unroll
    for (int d = 1; d < 1024; d <<= 1) {
        const int v = (t >= d) ? lds[t - d] : 0;
        __syncthreads();
        lds[t] += v;
        __syncthreads();
    }
    int run = lds[t] - s;
    for (int i = lo; i < hi; ++i) { const int c = a[i]; a[i] = run; run += c; }
}

__global__ __launch_bounds__(256) void copy_i32(
    const int* __restrict__ src, int* __restrict__ dst, int n)
{
    const int i = blockIdx.x * 256 + threadIdx.x;
    if (i < n) dst[i] = src[i];
}

// append packed (node_local, edge) entries into bucket segments
__global__ __launch_bounds__(256) void append_pairs(
    const int* __restrict__ idx, int* __restrict__ bcur,
    u32* __restrict__ buf, int E, int N)
{
    const bool idx64 = sniff_idx64(idx);
    const int i = blockIdx.x * 256 + threadIdx.x;   // endpoint slot < 2E
    if (i >= 2 * E) return;
    int node = idx64 ? idx[2 * (size_t)i] : idx[i];
    node = min(max(node, 0), N - 1);
    const int p = atomicAdd(&bcur[node >> 7], 1);
    buf[p] = ((u32)(node & 127) << 25) | (u32)(i >> 1);
}

// one block per bucket: accumulate 128 node rows in LDS, write sequentially
__global__ __launch_bounds__(256) void bucket_gather(
    const int* __restrict__ bstart,   // starts (post-scan, unmutated)
    const int* __restrict__ bend,     // bcur after append == ends
    const u32* __restrict__ buf,
    const float* __restrict__ edge_feat,   // [E,64] f32
    float* __restrict__ out_node, int N)
{
    __shared__ float lacc[128 * HID];   // 32 KB
    const int tid = threadIdx.x, wave = tid >> 6, lane = tid & 63;
    const int b = blockIdx.x;

    {
        float4 z = make_float4(0.f, 0.f, 0.f, 0.f);
        float4* l4 = (float4*)lacc;
        #pragma unroll
        for (int i = tid; i < 128 * HID / 4; i += 256) l4[i] = z;
    }
    __syncthreads();

    const int start = bstart[b], end = bend[b];

    // wave-strided batches of 8 entries; 8 outstanding row loads hide latency
    for (int base = start + wave * 8; base < end; base += 32) {
        u32 ent[8];
        #pragma unroll
        for (int u = 0; u < 8; ++u)
            ent[u] = (base + u < end) ? buf[base + u] : 0xFFFFFFFFu;
        float v[8];
        #pragma unroll
        for (int u = 0; u < 8; ++u)
            if (ent[u] != 0xFFFFFFFFu)
                v[u] = edge_feat[(size_t)(ent[u] & 0x1FFFFFFu) * HID + lane];
        #pragma unroll
        for (int u = 0; u < 8; ++u)
            if (ent[u] != 0xFFFFFFFFu)
                atomicAdd(&lacc[(int)(ent[u] >> 25) * HID + lane], v[u]);
    }
    __syncthreads();

    const int node0 = b << 7;
    const float4* l4 = (const float4*)lacc;
    float4* o4 = (float4*)out_node;
    for (int i = tid; i < 128 * (HID / 4); i += 256) {
        const int nl = i >> 4, q = i & 15;
        const int node = node0 + nl;
        if (node < N) o4[(size_t)node * (HID / 4) + q] = l4[i];
    }
}

// ---------------- weight packing into B-fragment order ----------------
__global__ __launch_bounds__(256) void pack_weights(
    const float* __restrict__ W1, const float* __restrict__ W2,
    const float* __restrict__ W3, const float* __restrict__ W4,
    ush* __restrict__ pack)
{
    const int i = blockIdx.x * 256 + threadIdx.x;
    if (i >= 14336) return;
    const float* W; int base;
    if (i < 2048)       { W = W1; base = 0; }
    else if (i < 6144)  { W = W2; base = 2048; }
    else if (i < 10240) { W = W3; base = 6144; }
    else                { W = W4; base = 10240; }
    const int j = i - base;
    const int e = j & 7, l = (j >> 3) & 63, f = j >> 9;
    const int ct = f & 3, kc = f >> 2;
    const int k = kc * 32 + ((l >> 4) << 3) + e;
    const int col = ct * 16 + (l & 15);
    pack[i] = f2b(W[k * HID + col]);
}

// ---------------- MFMA MLP + LayerNorm (unchanged from round 5) ----------------
__global__ __launch_bounds__(256, 2) void mlp_ln_mfma(
    const float* __restrict__ x,       // [E,32] f32
    const ush* __restrict__ packW,     // 14336 bf16
    const float* __restrict__ b1, const float* __restrict__ b2,
    const float* __restrict__ b3, const float* __restrict__ b4,
    const float* __restrict__ gamma, const float* __restrict__ beta,
    float* __restrict__ out_edge,      // [E,64] f32
    int E)
{
    __shared__ float sB[6 * HID];
    __shared__ __align__(16) ush hbuf[4][16 * 72];

    const int tid = threadIdx.x;
    const int wave = tid >> 6, lane = tid & 63;
    if (tid < HID) {
        sB[tid]           = b1[tid];
        sB[HID + tid]     = b2[tid];
        sB[2 * HID + tid] = b3[tid];
        sB[3 * HID + tid] = b4[tid];
        sB[4 * HID + tid] = gamma[tid];
        sB[5 * HID + tid] = beta[tid];
    }
    __syncthreads();

    const bf16x8* pw = (const bf16x8*)packW;
    bf16x8 w1[4], w2[8], w3[8], w4[8];
    #pragma unroll
    for (int f = 0; f < 4; ++f) w1[f] = pw[f * 64 + lane];
    #pragma unroll
    for (int f = 0; f < 8; ++f) w2[f] = pw[256 + f * 64 + lane];
    #pragma unroll
    for (int f = 0; f < 8; ++f) w3[f] = pw[768 + f * 64 + lane];
    #pragma unroll
    for (int f = 0; f < 8; ++f) w4[f] = pw[1280 + f * 64 + lane];

    ush* hb = &hbuf[wave][0];
    const int l15 = lane & 15, lg = lane >> 4;

    for (int s = 0; s < 2; ++s) {
        const int rowBase = blockIdx.x * 128 + wave * 32 + s * 16;

        const int rr = min(rowBase + l15, E - 1);
        const float4* xp = (const float4*)(x + (size_t)rr * IN_DIM + lg * 8);
        const float4 xa = xp[0], xb = xp[1];
        bf16x8 aL1;
        aL1[0] = (short)f2b(xa.x); aL1[1] = (short)f2b(xa.y);
        aL1[2] = (short)f2b(xa.z); aL1[3] = (short)f2b(xa.w);
        aL1[4] = (short)f2b(xb.x); aL1[5] = (short)f2b(xb.y);
        aL1[6] = (short)f2b(xb.z); aL1[7] = (short)f2b(xb.w);

        f32x4 acc[4];

        #pragma unroll
        for (int ct = 0; ct < 4; ++ct) {
            const float bv = sB[0 * HID + ct * 16 + l15];
            f32x4 c = {bv, bv, bv, bv};
            c = __builtin_amdgcn_mfma_f32_16x16x32_bf16(aL1, w1[ct], c, 0, 0, 0);
            acc[ct] = c;
        }

        #pragma unroll
        for (int ct = 0; ct < 4; ++ct)
            #pragma unroll
            for (int r = 0; r < 4; ++r) {
                float v = acc[ct][r]; v = v > 0.f ? v : 0.f;
                hb[(lg * 4 + r) * 72 + ct * 16 + l15] = f2b(v);
            }

        #define LAYER(WARR, BIDX, RELU_) do {                                   \
            const bf16x8 a0 = *(const bf16x8*)&hb[l15 * 72 + 0 * 32 + lg * 8];  \
            const bf16x8 a1 = *(const bf16x8*)&hb[l15 * 72 + 1 * 32 + lg * 8];  \
            _Pragma("unroll")                                                   \
            for (int ct = 0; ct < 4; ++ct) {                                    \
                const float bv = sB[(BIDX) * HID + ct * 16 + l15];              \
                f32x4 c = {bv, bv, bv, bv};                                     \
                c = __builtin_amdgcn_mfma_f32_16x16x32_bf16(a0, WARR[ct], c, 0, 0, 0);      \
                c = __builtin_amdgcn_mfma_f32_16x16x32_bf16(a1, WARR[4 + ct], c, 0, 0, 0);  \
                acc[ct] = c;                                                    \
            }                                                                   \
            if (RELU_) {                                                        \
                _Pragma("unroll")                                               \
                for (int ct = 0; ct < 4; ++ct)                                  \
                    _Pragma("unroll")                                           \
                    for (int r = 0; r < 4; ++r) {                               \
                        float v = acc[ct][r]; v = v > 0.f ? v : 0.f;            \
                        hb[(lg * 4 + r) * 72 + ct * 16 + l15] = f2b(v);         \
                    }                                                           \
            }                                                                   \
        } while (0)

        LAYER(w2, 1, 1);
        LAYER(w3, 2, 1);
        LAYER(w4, 3, 0);
        #undef LAYER

        float s1[4], s2[4];
        #pragma unroll
        for (int r = 0; r < 4; ++r) {
            float a = acc[0][r] + acc[1][r] + acc[2][r] + acc[3][r];
            float q = acc[0][r] * acc[0][r] + acc[1][r] * acc[1][r]
                    + acc[2][r] * acc[2][r] + acc[3][r] * acc[3][r];
            #pragma unroll
            for (int m = 1; m < 16; m <<= 1) {
                a += __shfl_xor(a, m, 64);
                q += __shfl_xor(q, m, 64);
            }
            s1[r] = a; s2[r] = q;
        }

        #pragma unroll
        for (int r = 0; r < 4; ++r) {
            const float mu = s1[r] * (1.0f / HID);
            const float varr = fmaxf(s2[r] * (1.0f / HID) - mu * mu, 0.f);
            const float inv = rsqrtf(varr + LN_EPS);
            const int row = rowBase + lg * 4 + r;
            if (row < E) {
                float* op = out_edge + (size_t)row * HID;
                #pragma unroll
                for (int ct = 0; ct < 4; ++ct) {
                    const float g = sB[4 * HID + ct * 16 + l15];
                    const float bt = sB[5 * HID + ct * 16 + l15];
                    op[ct * 16 + l15] = g * (acc[ct][r] - mu) * inv + bt;
                }
            }
        }
    }
}

// ---------------- fallback: VALU kernel with atomics (ws too small) ----------------
__global__ __launch_bounds__(256) void mlp_ln_scatter_fb(
    const float* __restrict__ x, const int* __restrict__ idx,
    const float* __restrict__ W1, const float* __restrict__ b1,
    const float* __restrict__ W2, const float* __restrict__ b2,
    const float* __restrict__ W3, const float* __restrict__ b3,
    const float* __restrict__ W4, const float* __restrict__ b4,
    const float* __restrict__ gamma, const float* __restrict__ beta,
    float* __restrict__ out_edge, float* __restrict__ node_acc, int E, int N)
{
    __shared__ float sW1[IN_DIM * HID];
    __shared__ float sW2[HID * HID];
    __shared__ float sW3[HID * HID];
    __shared__ float sW4[HID * HID];
    __shared__ float sB[6 * HID];
    const int tid = threadIdx.x;
    {
        const float4* W1v = (const float4*)W1;
        float4* s1 = (float4*)sW1;
        for (int i = tid; i < IN_DIM * HID / 4; i += 256) s1[i] = W1v[i];
        const float4* W2v = (const float4*)W2;
        const float4* W3v = (const float4*)W3;
        const float4* W4v = (const float4*)W4;
        float4* s2 = (float4*)sW2; float4* s3 = (float4*)sW3; float4* s4 = (float4*)sW4;
        for (int i = tid; i < HID * HID / 4; i += 256) { s2[i] = W2v[i]; s3[i] = W3v[i]; s4[i] = W4v[i]; }
        if (tid < HID) {
            sB[tid] = b1[tid]; sB[HID + tid] = b2[tid]; sB[2 * HID + tid] = b3[tid];
            sB[3 * HID + tid] = b4[tid]; sB[4 * HID + tid] = gamma[tid]; sB[5 * HID + tid] = beta[tid];
        }
    }
    __syncthreads();
    const int e = blockIdx.x * 256 + tid;
    if (e >= E) return;
    float h0[IN_DIM];
    {
        const float4* xv = (const float4*)(x + (size_t)e * IN_DIM);
        #pragma unroll
        for (int c = 0; c < 8; ++c) {
            const float4 v = xv[c];
            h0[c * 4 + 0] = v.x; h0[c * 4 + 1] = v.y; h0[c * 4 + 2] = v.z; h0[c * 4 + 3] = v.w;
        }
    }
    float a[HID], h[HID];
    #pragma unroll
    for (int j = 0; j < HID; ++j) a[j] = sB[j];
    #pragma unroll
    for (int k = 0; k < IN_DIM; ++k) {
        const float hk = h0[k];
        #pragma unroll
        for (int j = 0; j < HID; ++j) a[j] = fmaf(hk, sW1[k * HID + j], a[j]);
    }
    #pragma unroll
    for (int j = 0; j < HID; ++j) h[j] = a[j] > 0.f ? a[j] : 0.f;
    #pragma unroll
    for (int j = 0; j < HID; ++j) a[j] = sB[HID + j];
    #pragma unroll
    for (int k = 0; k < HID; ++k) {
        const float hk = h[k];
        #pragma unroll
        for (int j = 0; j < HID; ++j) a[j] = fmaf(hk, sW2[k * HID + j], a[j]);
    }
    #pragma unroll
    for (int j = 0; j < HID; ++j) h[j] = a[j] > 0.f ? a[j] : 0.f;
    #pragma unroll
    for (int j = 0; j < HID; ++j) a[j] = sB[2 * HID + j];
    #pragma unroll
    for (int k = 0; k < HID; ++k) {
        const float hk = h[k];
        #pragma unroll
        for (int j = 0; j < HID; ++j) a[j] = fmaf(hk, sW3[k * HID + j], a[j]);
    }
    #pragma unroll
    for (int j = 0; j < HID; ++j) h[j] = a[j] > 0.f ? a[j] : 0.f;
    #pragma unroll
    for (int j = 0; j < HID; ++j) a[j] = sB[3 * HID + j];
    #pragma unroll
    for (int k = 0; k < HID; ++k) {
        const float hk = h[k];
        #pragma unroll
        for (int j = 0; j < HID; ++j) a[j] = fmaf(hk, sW4[k * HID + j], a[j]);
    }
    float s = 0.f;
    #pragma unroll
    for (int j = 0; j < HID; ++j) s += a[j];
    const float mu = s * (1.0f / HID);
    float s2 = 0.f;
    #pragma unroll
    for (int j = 0; j < HID; ++j) { const float d = a[j] - mu; s2 += d * d; }
    const float inv = rsqrtf(s2 * (1.0f / HID) + LN_EPS);
    #pragma unroll
    for (int j = 0; j < HID; ++j)
        a[j] = sB[4 * HID + j] * ((a[j] - mu) * inv) + sB[5 * HID + j];
    {
        float4* oe = (float4*)(out_edge + (size_t)e * HID);
        #pragma unroll
        for (int c = 0; c < 16; ++c)
            oe[c] = make_float4(a[c * 4], a[c * 4 + 1], a[c * 4 + 2], a[c * 4 + 3]);
    }
    const bool idx64 = sniff_idx64(idx);
    int na, nb;
    if (idx64) { na = idx[4 * (size_t)e]; nb = idx[4 * (size_t)e + 2]; }
    else       { na = idx[2 * (size_t)e]; nb = idx[2 * (size_t)e + 1]; }
    na = min(max(na, 0), N - 1);
    nb = min(max(nb, 0), N - 1);
    float* pa = node_acc + (size_t)na * HID;
    float* pb = node_acc + (size_t)nb * HID;
    #pragma unroll
    for (int j = 0; j < HID; ++j) {
        unsafeAtomicAdd(pa + j, a[j]);
        unsafeAtomicAdd(pb + j, a[j]);
    }
}

extern "C" void kernel_launch(void* const* d_in, const int* in_sizes, int n_in,
                              void* d_out, int out_size, void* d_ws, size_t ws_size,
                              hipStream_t stream) {
    const float* x     = (const float*)d_in[0];
    const int*   idx   = (const int*)d_in[1];
    const float* W1    = (const float*)d_in[3];
    const float* b1    = (const float*)d_in[4];
    const float* W2    = (const float*)d_in[5];
    const float* b2    = (const float*)d_in[6];
    const float* W3    = (const float*)d_in[7];
    const float* b3    = (const float*)d_in[8];
    const float* W4    = (const float*)d_in[9];
    const float* b4    = (const float*)d_in[10];
    const float* gamma = (const float*)d_in[11];
    const float* beta  = (const float*)d_in[12];

    const int E = in_sizes[0] / IN_DIM;
    const int N = out_size / HID - E;
    const int NB = (N + 127) >> 7;               // 128-node buckets

    float* out_node = (float*)d_out;
    float* out_edge = out_node + (size_t)N * HID;

    // ws layout: pack(28KB) | bstart[NB] | bcur[NB] | buf[2E] u32
    const size_t packOff  = 0;
    const size_t bstartOff = 32768;
    const size_t bcurOff   = bstartOff + ((size_t)NB * 4 + 255 & ~255ull);
    const size_t bufOff    = bcurOff + ((size_t)NB * 4 + 255 & ~255ull);
    const size_t need      = bufOff + (size_t)2 * E * sizeof(u32);

    if (ws_size >= need) {
        ush* pack   = (ush*)((char*)d_ws + packOff);
        int* bstart = (int*)((char*)d_ws + bstartOff);
        int* bcur   = (int*)((char*)d_ws + bcurOff);
        u32* buf    = (u32*)((char*)d_ws + bufOff);

        pack_weights<<<(14336 + 255) / 256, 256, 0, stream>>>(W1, W2, W3, W4, pack);
        zero_i32<<<(NB + 255) / 256, 256, 0, stream>>>(bstart, NB);
        bucket_count<<<(2 * E + 255) / 256, 256, 0, stream>>>(idx, bstart, E, N);
        scan_excl<<<1, 1024, 0, stream>>>(bstart, NB);
        copy_i32<<<(NB + 255) / 256, 256, 0, stream>>>(bstart, bcur, NB);
        append_pairs<<<(2 * E + 255) / 256, 256, 0, stream>>>(idx, bcur, buf, E, N);
        mlp_ln_mfma<<<(E + 127) / 128, 256, 0, stream>>>(
            x, pack, b1, b2, b3, b4, gamma, beta, out_edge, E);
        bucket_gather<<<NB, 256, 0, stream>>>(bstart, bcur, buf, out_edge, out_node, N);
    } else {
        const int n16 = (int)(((size_t)N * HID * sizeof(float)) / 16);
        zero16<<<(n16 + 255) / 256, 256, 0, stream>>>((uint4*)out_node, n16);
        mlp_ln_scatter_fb<<<(E + 255) / 256, 256, 0, stream>>>(
            x, idx, W1, b1, W2, b2, W3, b3, W4, b4, gamma, beta,
            out_edge, out_node, E, N);
    }
}

// Round 7
// 1780.719 us; speedup vs baseline: 3.3866x; 3.3866x over previous
//
#include <hip/hip_runtime.h>

#define IN_DIM 32
#define HID 64
#define LN_EPS 1e-5f
#define BSH 3                 // 8 nodes per bucket

typedef unsigned short ush;
typedef unsigned int u32;
typedef __attribute__((ext_vector_type(8))) short bf16x8;
typedef __attribute__((ext_vector_type(4))) float f32x4;

static __device__ __forceinline__ ush f2b(float f) {
    union { float f; unsigned int i; } v; v.f = f;
    unsigned int x = v.i;
    return (ush)((x + 0x7fffu + ((x >> 16) & 1u)) >> 16);  // RNE
}

__global__ __launch_bounds__(256) void zero_i32(int* __restrict__ p, int n) {
    const int i = blockIdx.x * 256 + threadIdx.x;
    if (i < n) p[i] = 0;
}

__global__ __launch_bounds__(256) void zero16(uint4* __restrict__ p, int n16) {
    const int i = blockIdx.x * 256 + threadIdx.x;
    if (i < n16) p[i] = make_uint4(0u, 0u, 0u, 0u);
}

static __device__ __forceinline__ bool sniff_idx64(const int* idx) {
    int zc = 0;
    #pragma unroll
    for (int t = 0; t < 8; ++t) zc += (idx[2 * t + 1] == 0) ? 1 : 0;
    return zc >= 7;
}

// ---- bucket pipeline: bucket = node >> BSH ----

__global__ __launch_bounds__(256) void bucket_count(
    const int* __restrict__ idx, int* __restrict__ bcnt, int E, int N)
{
    const bool idx64 = sniff_idx64(idx);
    const int i = blockIdx.x * 256 + threadIdx.x;   // endpoint slot < 2E
    if (i >= 2 * E) return;
    int node = idx64 ? idx[2 * (size_t)i] : idx[i];
    node = min(max(node, 0), N - 1);
    atomicAdd(&bcnt[node >> BSH], 1);
}

// in-place exclusive scan over a[0..n); also writes the result to b[]
__global__ __launch_bounds__(1024) void scan_excl2(
    int* __restrict__ a, int* __restrict__ b, int n)
{
    __shared__ int lds[1024];
    const int t = threadIdx.x;
    const int L = (n + 1023) >> 10;
    const int lo = t * L, hi = min(n, lo + L);
    int s = 0;
    for (int i = lo; i < hi; ++i) s += a[i];
    lds[t] = s;
    __syncthreads();
    #pragma unroll
    for (int d = 1; d < 1024; d <<= 1) {
        const int v = (t >= d) ? lds[t - d] : 0;
        __syncthreads();
        lds[t] += v;
        __syncthreads();
    }
    int run = lds[t] - s;
    for (int i = lo; i < hi; ++i) {
        const int c = a[i];
        a[i] = run; b[i] = run;
        run += c;
    }
}

// append packed (node_local, edge) entries into bucket segments
__global__ __launch_bounds__(256) void append_pairs(
    const int* __restrict__ idx, int* __restrict__ bcur,
    u32* __restrict__ buf, int E, int N)
{
    const bool idx64 = sniff_idx64(idx);
    const int i = blockIdx.x * 256 + threadIdx.x;   // endpoint slot < 2E
    if (i >= 2 * E) return;
    int node = idx64 ? idx[2 * (size_t)i] : idx[i];
    node = min(max(node, 0), N - 1);
    const int p = atomicAdd(&bcur[node >> BSH], 1);
    buf[p] = ((u32)(node & ((1 << BSH) - 1)) << 29) | (u32)(i >> 1);
}

// one 64-lane wave per node; lane = feature; filter-scan the node's bucket
__global__ __launch_bounds__(256) void node_gather(
    const int* __restrict__ bstart,   // bucket segment starts
    const int* __restrict__ bend,     // bcur after append == segment ends
    const u32* __restrict__ buf,
    const float* __restrict__ edge_feat,   // [E,64] f32
    float* __restrict__ out_node, int N)
{
    const int w = (blockIdx.x * 256 + threadIdx.x) >> 6;
    const int lane = threadIdx.x & 63;
    if (w >= N) return;
    const int b = w >> BSH;
    const u32 key = (u32)(w & ((1 << BSH) - 1)) << 29;
    const int s = bstart[b], e = bend[b];

    float acc = 0.f;
    int i = s;
    for (; i + 16 <= e; i += 16) {
        u32 ent[16];
        #pragma unroll
        for (int u = 0; u < 16; ++u) ent[u] = buf[i + u];   // wave-uniform broadcast
        float v[16];
        #pragma unroll
        for (int u = 0; u < 16; ++u)
            if ((ent[u] & 0xE0000000u) == key)
                v[u] = edge_feat[(size_t)(ent[u] & 0x1FFFFFFFu) * HID + lane];
        #pragma unroll
        for (int u = 0; u < 16; ++u)
            if ((ent[u] & 0xE0000000u) == key) acc += v[u];
    }
    for (; i < e; ++i) {
        const u32 en = buf[i];
        if ((en & 0xE0000000u) == key)
            acc += edge_feat[(size_t)(en & 0x1FFFFFFFu) * HID + lane];
    }
    out_node[(size_t)w * HID + lane] = acc;
}

// ---------------- weight packing into B-fragment order ----------------
__global__ __launch_bounds__(256) void pack_weights(
    const float* __restrict__ W1, const float* __restrict__ W2,
    const float* __restrict__ W3, const float* __restrict__ W4,
    ush* __restrict__ pack)
{
    const int i = blockIdx.x * 256 + threadIdx.x;
    if (i >= 14336) return;
    const float* W; int base;
    if (i < 2048)       { W = W1; base = 0; }
    else if (i < 6144)  { W = W2; base = 2048; }
    else if (i < 10240) { W = W3; base = 6144; }
    else                { W = W4; base = 10240; }
    const int j = i - base;
    const int e = j & 7, l = (j >> 3) & 63, f = j >> 9;
    const int ct = f & 3, kc = f >> 2;
    const int k = kc * 32 + ((l >> 4) << 3) + e;
    const int col = ct * 16 + (l & 15);
    pack[i] = f2b(W[k * HID + col]);
}

// ---------------- MFMA MLP + LayerNorm (unchanged, proven) ----------------
__global__ __launch_bounds__(256, 2) void mlp_ln_mfma(
    const float* __restrict__ x,       // [E,32] f32
    const ush* __restrict__ packW,     // 14336 bf16
    const float* __restrict__ b1, const float* __restrict__ b2,
    const float* __restrict__ b3, const float* __restrict__ b4,
    const float* __restrict__ gamma, const float* __restrict__ beta,
    float* __restrict__ out_edge,      // [E,64] f32
    int E)
{
    __shared__ float sB[6 * HID];
    __shared__ __align__(16) ush hbuf[4][16 * 72];

    const int tid = threadIdx.x;
    const int wave = tid >> 6, lane = tid & 63;
    if (tid < HID) {
        sB[tid]           = b1[tid];
        sB[HID + tid]     = b2[tid];
        sB[2 * HID + tid] = b3[tid];
        sB[3 * HID + tid] = b4[tid];
        sB[4 * HID + tid] = gamma[tid];
        sB[5 * HID + tid] = beta[tid];
    }
    __syncthreads();

    const bf16x8* pw = (const bf16x8*)packW;
    bf16x8 w1[4], w2[8], w3[8], w4[8];
    #pragma unroll
    for (int f = 0; f < 4; ++f) w1[f] = pw[f * 64 + lane];
    #pragma unroll
    for (int f = 0; f < 8; ++f) w2[f] = pw[256 + f * 64 + lane];
    #pragma unroll
    for (int f = 0; f < 8; ++f) w3[f] = pw[768 + f * 64 + lane];
    #pragma unroll
    for (int f = 0; f < 8; ++f) w4[f] = pw[1280 + f * 64 + lane];

    ush* hb = &hbuf[wave][0];
    const int l15 = lane & 15, lg = lane >> 4;

    for (int s = 0; s < 2; ++s) {
        const int rowBase = blockIdx.x * 128 + wave * 32 + s * 16;

        const int rr = min(rowBase + l15, E - 1);
        const float4* xp = (const float4*)(x + (size_t)rr * IN_DIM + lg * 8);
        const float4 xa = xp[0], xb = xp[1];
        bf16x8 aL1;
        aL1[0] = (short)f2b(xa.x); aL1[1] = (short)f2b(xa.y);
        aL1[2] = (short)f2b(xa.z); aL1[3] = (short)f2b(xa.w);
        aL1[4] = (short)f2b(xb.x); aL1[5] = (short)f2b(xb.y);
        aL1[6] = (short)f2b(xb.z); aL1[7] = (short)f2b(xb.w);

        f32x4 acc[4];

        #pragma unroll
        for (int ct = 0; ct < 4; ++ct) {
            const float bv = sB[0 * HID + ct * 16 + l15];
            f32x4 c = {bv, bv, bv, bv};
            c = __builtin_amdgcn_mfma_f32_16x16x32_bf16(aL1, w1[ct], c, 0, 0, 0);
            acc[ct] = c;
        }

        #pragma unroll
        for (int ct = 0; ct < 4; ++ct)
            #pragma unroll
            for (int r = 0; r < 4; ++r) {
                float v = acc[ct][r]; v = v > 0.f ? v : 0.f;
                hb[(lg * 4 + r) * 72 + ct * 16 + l15] = f2b(v);
            }

        #define LAYER(WARR, BIDX, RELU_) do {                                   \
            const bf16x8 a0 = *(const bf16x8*)&hb[l15 * 72 + 0 * 32 + lg * 8];  \
            const bf16x8 a1 = *(const bf16x8*)&hb[l15 * 72 + 1 * 32 + lg * 8];  \
            _Pragma("unroll")                                                   \
            for (int ct = 0; ct < 4; ++ct) {                                    \
                const float bv = sB[(BIDX) * HID + ct * 16 + l15];              \
                f32x4 c = {bv, bv, bv, bv};                                     \
                c = __builtin_amdgcn_mfma_f32_16x16x32_bf16(a0, WARR[ct], c, 0, 0, 0);      \
                c = __builtin_amdgcn_mfma_f32_16x16x32_bf16(a1, WARR[4 + ct], c, 0, 0, 0);  \
                acc[ct] = c;                                                    \
            }                                                                   \
            if (RELU_) {                                                        \
                _Pragma("unroll")                                               \
                for (int ct = 0; ct < 4; ++ct)                                  \
                    _Pragma("unroll")                                           \
                    for (int r = 0; r < 4; ++r) {                               \
                        float v = acc[ct][r]; v = v > 0.f ? v : 0.f;            \
                        hb[(lg * 4 + r) * 72 + ct * 16 + l15] = f2b(v);         \
                    }                                                           \
            }                                                                   \
        } while (0)

        LAYER(w2, 1, 1);
        LAYER(w3, 2, 1);
        LAYER(w4, 3, 0);
        #undef LAYER

        float s1[4], s2[4];
        #pragma unroll
        for (int r = 0; r < 4; ++r) {
            float a = acc[0][r] + acc[1][r] + acc[2][r] + acc[3][r];
            float q = acc[0][r] * acc[0][r] + acc[1][r] * acc[1][r]
                    + acc[2][r] * acc[2][r] + acc[3][r] * acc[3][r];
            #pragma unroll
            for (int m = 1; m < 16; m <<= 1) {
                a += __shfl_xor(a, m, 64);
                q += __shfl_xor(q, m, 64);
            }
            s1[r] = a; s2[r] = q;
        }

        #pragma unroll
        for (int r = 0; r < 4; ++r) {
            const float mu = s1[r] * (1.0f / HID);
            const float varr = fmaxf(s2[r] * (1.0f / HID) - mu * mu, 0.f);
            const float inv = rsqrtf(varr + LN_EPS);
            const int row = rowBase + lg * 4 + r;
            if (row < E) {
                float* op = out_edge + (size_t)row * HID;
                #pragma unroll
                for (int ct = 0; ct < 4; ++ct) {
                    const float g = sB[4 * HID + ct * 16 + l15];
                    const float bt = sB[5 * HID + ct * 16 + l15];
                    op[ct * 16 + l15] = g * (acc[ct][r] - mu) * inv + bt;
                }
            }
        }
    }
}

// ---------------- fallback: VALU kernel with atomics (ws too small) ----------------
__global__ __launch_bounds__(256) void mlp_ln_scatter_fb(
    const float* __restrict__ x, const int* __restrict__ idx,
    const float* __restrict__ W1, const float* __restrict__ b1,
    const float* __restrict__ W2, const float* __restrict__ b2,
    const float* __restrict__ W3, const float* __restrict__ b3,
    const float* __restrict__ W4, const float* __restrict__ b4,
    const float* __restrict__ gamma, const float* __restrict__ beta,
    float* __restrict__ out_edge, float* __restrict__ node_acc, int E, int N)
{
    __shared__ float sW1[IN_DIM * HID];
    __shared__ float sW2[HID * HID];
    __shared__ float sW3[HID * HID];
    __shared__ float sW4[HID * HID];
    __shared__ float sB[6 * HID];
    const int tid = threadIdx.x;
    {
        const float4* W1v = (const float4*)W1;
        float4* s1 = (float4*)sW1;
        for (int i = tid; i < IN_DIM * HID / 4; i += 256) s1[i] = W1v[i];
        const float4* W2v = (const float4*)W2;
        const float4* W3v = (const float4*)W3;
        const float4* W4v = (const float4*)W4;
        float4* s2 = (float4*)sW2; float4* s3 = (float4*)sW3; float4* s4 = (float4*)sW4;
        for (int i = tid; i < HID * HID / 4; i += 256) { s2[i] = W2v[i]; s3[i] = W3v[i]; s4[i] = W4v[i]; }
        if (tid < HID) {
            sB[tid] = b1[tid]; sB[HID + tid] = b2[tid]; sB[2 * HID + tid] = b3[tid];
            sB[3 * HID + tid] = b4[tid]; sB[4 * HID + tid] = gamma[tid]; sB[5 * HID + tid] = beta[tid];
        }
    }
    __syncthreads();
    const int e = blockIdx.x * 256 + tid;
    if (e >= E) return;
    float h0[IN_DIM];
    {
        const float4* xv = (const float4*)(x + (size_t)e * IN_DIM);
        #pragma unroll
        for (int c = 0; c < 8; ++c) {
            const float4 v = xv[c];
            h0[c * 4 + 0] = v.x; h0[c * 4 + 1] = v.y; h0[c * 4 + 2] = v.z; h0[c * 4 + 3] = v.w;
        }
    }
    float a[HID], h[HID];
    #pragma unroll
    for (int j = 0; j < HID; ++j) a[j] = sB[j];
    #pragma unroll
    for (int k = 0; k < IN_DIM; ++k) {
        const float hk = h0[k];
        #pragma unroll
        for (int j = 0; j < HID; ++j) a[j] = fmaf(hk, sW1[k * HID + j], a[j]);
    }
    #pragma unroll
    for (int j = 0; j < HID; ++j) h[j] = a[j] > 0.f ? a[j] : 0.f;
    #pragma unroll
    for (int j = 0; j < HID; ++j) a[j] = sB[HID + j];
    #pragma unroll
    for (int k = 0; k < HID; ++k) {
        const float hk = h[k];
        #pragma unroll
        for (int j = 0; j < HID; ++j) a[j] = fmaf(hk, sW2[k * HID + j], a[j]);
    }
    #pragma unroll
    for (int j = 0; j < HID; ++j) h[j] = a[j] > 0.f ? a[j] : 0.f;
    #pragma unroll
    for (int j = 0; j < HID; ++j) a[j] = sB[2 * HID + j];
    #pragma unroll
    for (int k = 0; k < HID; ++k) {
        const float hk = h[k];
        #pragma unroll
        for (int j = 0; j < HID; ++j) a[j] = fmaf(hk, sW3[k * HID + j], a[j]);
    }
    #pragma unroll
    for (int j = 0; j < HID; ++j) h[j] = a[j] > 0.f ? a[j] : 0.f;
    #pragma unroll
    for (int j = 0; j < HID; ++j) a[j] = sB[3 * HID + j];
    #pragma unroll
    for (int k = 0; k < HID; ++k) {
        const float hk = h[k];
        #pragma unroll
        for (int j = 0; j < HID; ++j) a[j] = fmaf(hk, sW4[k * HID + j], a[j]);
    }
    float s = 0.f;
    #pragma unroll
    for (int j = 0; j < HID; ++j) s += a[j];
    const float mu = s * (1.0f / HID);
    float s2 = 0.f;
    #pragma unroll
    for (int j = 0; j < HID; ++j) { const float d = a[j] - mu; s2 += d * d; }
    const float inv = rsqrtf(s2 * (1.0f / HID) + LN_EPS);
    #pragma unroll
    for (int j = 0; j < HID; ++j)
        a[j] = sB[4 * HID + j] * ((a[j] - mu) * inv) + sB[5 * HID + j];
    {
        float4* oe = (float4*)(out_edge + (size_t)e * HID);
        #pragma unroll
        for (int c = 0; c < 16; ++c)
            oe[c] = make_float4(a[c * 4], a[c * 4 + 1], a[c * 4 + 2], a[c * 4 + 3]);
    }
    const bool idx64 = sniff_idx64(idx);
    int na, nb;
    if (idx64) { na = idx[4 * (size_t)e]; nb = idx[4 * (size_t)e + 2]; }
    else       { na = idx[2 * (size_t)e]; nb = idx[2 * (size_t)e + 1]; }
    na = min(max(na, 0), N - 1);
    nb = min(max(nb, 0), N - 1);
    float* pa = node_acc + (size_t)na * HID;
    float* pb = node_acc + (size_t)nb * HID;
    #pragma unroll
    for (int j = 0; j < HID; ++j) {
        unsafeAtomicAdd(pa + j, a[j]);
        unsafeAtomicAdd(pb + j, a[j]);
    }
}

extern "C" void kernel_launch(void* const* d_in, const int* in_sizes, int n_in,
                              void* d_out, int out_size, void* d_ws, size_t ws_size,
                              hipStream_t stream) {
    const float* x     = (const float*)d_in[0];
    const int*   idx   = (const int*)d_in[1];
    const float* W1    = (const float*)d_in[3];
    const float* b1    = (const float*)d_in[4];
    const float* W2    = (const float*)d_in[5];
    const float* b2    = (const float*)d_in[6];
    const float* W3    = (const float*)d_in[7];
    const float* b3    = (const float*)d_in[8];
    const float* W4    = (const float*)d_in[9];
    const float* b4    = (const float*)d_in[10];
    const float* gamma = (const float*)d_in[11];
    const float* beta  = (const float*)d_in[12];

    const int E = in_sizes[0] / IN_DIM;
    const int N = out_size / HID - E;
    const int NB = (N + (1 << BSH) - 1) >> BSH;   // 8-node buckets

    float* out_node = (float*)d_out;
    float* out_edge = out_node + (size_t)N * HID;

    // ws layout: pack(32KB) | bstart[NB] | bcur[NB] | buf[2E] u32
    const size_t bstartOff = 32768;
    const size_t bcurOff   = bstartOff + (((size_t)NB * 4 + 255) & ~255ull);
    const size_t bufOff    = bcurOff + (((size_t)NB * 4 + 255) & ~255ull);
    const size_t need      = bufOff + (size_t)2 * E * sizeof(u32);

    if (ws_size >= need) {
        ush* pack   = (ush*)d_ws;
        int* bstart = (int*)((char*)d_ws + bstartOff);
        int* bcur   = (int*)((char*)d_ws + bcurOff);
        u32* buf    = (u32*)((char*)d_ws + bufOff);

        pack_weights<<<(14336 + 255) / 256, 256, 0, stream>>>(W1, W2, W3, W4, pack);
        zero_i32<<<(NB + 255) / 256, 256, 0, stream>>>(bstart, NB);
        bucket_count<<<(2 * E + 255) / 256, 256, 0, stream>>>(idx, bstart, E, N);
        scan_excl2<<<1, 1024, 0, stream>>>(bstart, bcur, NB);
        append_pairs<<<(2 * E + 255) / 256, 256, 0, stream>>>(idx, bcur, buf, E, N);
        mlp_ln_mfma<<<(E + 127) / 128, 256, 0, stream>>>(
            x, pack, b1, b2, b3, b4, gamma, beta, out_edge, E);
        node_gather<<<(N * 64 + 255) / 256, 256, 0, stream>>>(
            bstart, bcur, buf, out_edge, out_node, N);
    } else {
        const int n16 = (int)(((size_t)N * HID * sizeof(float)) / 16);
        zero16<<<(n16 + 255) / 256, 256, 0, stream>>>((uint4*)out_node, n16);
        mlp_ln_scatter_fb<<<(E + 255) / 256, 256, 0, stream>>>(
            x, idx, W1, b1, W2, b2, W3, b3, W4, b4, gamma, beta,
            out_edge, out_node, E, N);
    }
}

// Round 8
// 1439.946 us; speedup vs baseline: 4.1880x; 1.2367x over previous
//
#include <hip/hip_runtime.h>

#define IN_DIM 32
#define HID 64
#define LN_EPS 1e-5f
#define BSH 3                 // 8 nodes per bucket
#define BCAP 1024             // max entries sortable per bucket (LDS staging)

typedef unsigned short ush;
typedef unsigned int u32;
typedef unsigned long long u64;
typedef __attribute__((ext_vector_type(8))) short bf16x8;
typedef __attribute__((ext_vector_type(4))) float f32x4;

static __device__ __forceinline__ ush f2b(float f) {
    union { float f; unsigned int i; } v; v.f = f;
    unsigned int x = v.i;
    return (ush)((x + 0x7fffu + ((x >> 16) & 1u)) >> 16);  // RNE
}

__global__ __launch_bounds__(256) void zero_i32(int* __restrict__ p, int n) {
    const int i = blockIdx.x * 256 + threadIdx.x;
    if (i < n) p[i] = 0;
}

__global__ __launch_bounds__(256) void zero16(uint4* __restrict__ p, int n16) {
    const int i = blockIdx.x * 256 + threadIdx.x;
    if (i < n16) p[i] = make_uint4(0u, 0u, 0u, 0u);
}

static __device__ __forceinline__ bool sniff_idx64(const int* idx) {
    int zc = 0;
    #pragma unroll
    for (int t = 0; t < 8; ++t) zc += (idx[2 * t + 1] == 0) ? 1 : 0;
    return zc >= 7;
}

// ---- bucket pipeline: bucket = node >> BSH ----

__global__ __launch_bounds__(256) void bucket_count(
    const int* __restrict__ idx, int* __restrict__ bcnt, int E, int N)
{
    const bool idx64 = sniff_idx64(idx);
    const int i = blockIdx.x * 256 + threadIdx.x;   // endpoint slot < 2E
    if (i >= 2 * E) return;
    int node = idx64 ? idx[2 * (size_t)i] : idx[i];
    node = min(max(node, 0), N - 1);
    atomicAdd(&bcnt[node >> BSH], 1);
}

// in-place exclusive scan over a[0..n); also writes the result to b[]
__global__ __launch_bounds__(1024) void scan_excl2(
    int* __restrict__ a, int* __restrict__ b, int n)
{
    __shared__ int lds[1024];
    const int t = threadIdx.x;
    const int L = (n + 1023) >> 10;
    const int lo = t * L, hi = min(n, lo + L);
    int s = 0;
    for (int i = lo; i < hi; ++i) s += a[i];
    lds[t] = s;
    __syncthreads();
    #pragma unroll
    for (int d = 1; d < 1024; d <<= 1) {
        const int v = (t >= d) ? lds[t - d] : 0;
        __syncthreads();
        lds[t] += v;
        __syncthreads();
    }
    int run = lds[t] - s;
    for (int i = lo; i < hi; ++i) {
        const int c = a[i];
        a[i] = run; b[i] = run;
        run += c;
    }
}

// append packed (node_local, edge) entries into bucket segments
__global__ __launch_bounds__(256) void append_pairs(
    const int* __restrict__ idx, int* __restrict__ bcur,
    u32* __restrict__ buf, int E, int N)
{
    const bool idx64 = sniff_idx64(idx);
    const int i = blockIdx.x * 256 + threadIdx.x;   // endpoint slot < 2E
    if (i >= 2 * E) return;
    int node = idx64 ? idx[2 * (size_t)i] : idx[i];
    node = min(max(node, 0), N - 1);
    const int p = atomicAdd(&bcur[node >> BSH], 1);
    buf[p] = ((u32)(node & ((1 << BSH) - 1)) << 29) | (u32)(i >> 1);
}

// in-bucket counting sort by 3-bit local node id; one wave per bucket.
// Rewrites buf[s,e) node-sorted (in place via LDS staging) and emits
// nstart[node] = absolute start of that node's sub-segment (-1 = overflow).
__global__ __launch_bounds__(256) void bucket_sort(
    const int* __restrict__ bstart, const int* __restrict__ bend,
    u32* __restrict__ buf, int* __restrict__ nstart, int NB, int N)
{
    __shared__ u32 stg[4][BCAP];
    const int tid = threadIdx.x, wave = tid >> 6, lane = tid & 63;
    const int b = blockIdx.x * 4 + wave;
    if (b >= NB) return;
    const int s = bstart[b], e = bend[b], len = e - s;
    const int node0 = b << BSH;

    if (len > BCAP) {   // pathological bucket: leave unsorted, mark nodes
        if (lane < 8 && node0 + lane < N) nstart[node0 + lane] = -1;
        return;
    }

    // stage to LDS
    for (int i = lane; i < len; i += 64) stg[wave][i] = buf[s + i];

    // per-lane key counts
    int c[8] = {0, 0, 0, 0, 0, 0, 0, 0};
    for (int i = lane; i < len; i += 64) ++c[stg[wave][i] >> 29];
    #pragma unroll
    for (int k = 0; k < 8; ++k) {
        int v = c[k];
        #pragma unroll
        for (int m = 1; m < 64; m <<= 1) v += __shfl_xor(v, m, 64);
        c[k] = v;   // wave total, uniform
    }
    // exclusive prefix over the 8 keys (uniform in registers)
    u32 run[8];
    {
        u32 acc = 0;
        #pragma unroll
        for (int k = 0; k < 8; ++k) { run[k] = acc; acc += (u32)c[k]; }
    }
    // emit node sub-segment starts
    if (lane < 8 && node0 + lane < N) nstart[node0 + lane] = s + (int)run[lane];

    // ballot multi-split scatter back to global (stable not required)
    for (int i0 = 0; i0 < len; i0 += 64) {
        const int i = i0 + lane;
        const bool val = i < len;
        const u32 ent = val ? stg[wave][i] : 0u;
        const int k = (int)(ent >> 29);
        u32 pos = 0;
        #pragma unroll
        for (int kk = 0; kk < 8; ++kk) {
            const u64 m = __ballot(val && (k == kk));
            if (val && k == kk)
                pos = run[kk] + (u32)__popcll(m & ((1ull << lane) - 1ull));
            run[kk] += (u32)__popcll(m);
        }
        if (val) buf[s + pos] = ent;
    }
}

// one 64-lane wave per node; lane = feature; exact sub-segment (sorted buf)
__global__ __launch_bounds__(256) void node_gather(
    const int* __restrict__ nstart,
    const int* __restrict__ bstart, const int* __restrict__ bend,
    const u32* __restrict__ buf,
    const float* __restrict__ edge_feat,   // [E,64] f32
    float* __restrict__ out_node, int N)
{
    const int w = (blockIdx.x * 256 + threadIdx.x) >> 6;
    const int lane = threadIdx.x & 63;
    if (w >= N) return;
    const int b = w >> BSH;

    float acc = 0.f;
    const int s0 = nstart[w];
    if (s0 >= 0) {
        const bool lastInB = ((w & ((1 << BSH) - 1)) == ((1 << BSH) - 1)) || (w == N - 1);
        const int e0 = lastInB ? bend[b] : nstart[w + 1];
        int i = s0;
        for (; i + 16 <= e0; i += 16) {
            u32 ent[16];
            #pragma unroll
            for (int u = 0; u < 16; ++u) ent[u] = buf[i + u];
            float v[16];
            #pragma unroll
            for (int u = 0; u < 16; ++u)
                v[u] = edge_feat[(size_t)(ent[u] & 0x1FFFFFFFu) * HID + lane];
            #pragma unroll
            for (int u = 0; u < 16; ++u) acc += v[u];
        }
        for (; i < e0; ++i)
            acc += edge_feat[(size_t)(buf[i] & 0x1FFFFFFFu) * HID + lane];
    } else {
        // overflow bucket: filter-scan (round-7 path)
        const u32 key = (u32)(w & ((1 << BSH) - 1)) << 29;
        const int s = bstart[b], e = bend[b];
        for (int i = s; i < e; ++i) {
            const u32 en = buf[i];
            if ((en & 0xE0000000u) == key)
                acc += edge_feat[(size_t)(en & 0x1FFFFFFFu) * HID + lane];
        }
    }
    out_node[(size_t)w * HID + lane] = acc;
}

// ---------------- weight packing into B-fragment order ----------------
__global__ __launch_bounds__(256) void pack_weights(
    const float* __restrict__ W1, const float* __restrict__ W2,
    const float* __restrict__ W3, const float* __restrict__ W4,
    ush* __restrict__ pack)
{
    const int i = blockIdx.x * 256 + threadIdx.x;
    if (i >= 14336) return;
    const float* W; int base;
    if (i < 2048)       { W = W1; base = 0; }
    else if (i < 6144)  { W = W2; base = 2048; }
    else if (i < 10240) { W = W3; base = 6144; }
    else                { W = W4; base = 10240; }
    const int j = i - base;
    const int e = j & 7, l = (j >> 3) & 63, f = j >> 9;
    const int ct = f & 3, kc = f >> 2;
    const int k = kc * 32 + ((l >> 4) << 3) + e;
    const int col = ct * 16 + (l & 15);
    pack[i] = f2b(W[k * HID + col]);
}

// ---------------- MFMA MLP + LayerNorm (unchanged, proven) ----------------
__global__ __launch_bounds__(256, 2) void mlp_ln_mfma(
    const float* __restrict__ x,       // [E,32] f32
    const ush* __restrict__ packW,     // 14336 bf16
    const float* __restrict__ b1, const float* __restrict__ b2,
    const float* __restrict__ b3, const float* __restrict__ b4,
    const float* __restrict__ gamma, const float* __restrict__ beta,
    float* __restrict__ out_edge,      // [E,64] f32
    int E)
{
    __shared__ float sB[6 * HID];
    __shared__ __align__(16) ush hbuf[4][16 * 72];

    const int tid = threadIdx.x;
    const int wave = tid >> 6, lane = tid & 63;
    if (tid < HID) {
        sB[tid]           = b1[tid];
        sB[HID + tid]     = b2[tid];
        sB[2 * HID + tid] = b3[tid];
        sB[3 * HID + tid] = b4[tid];
        sB[4 * HID + tid] = gamma[tid];
        sB[5 * HID + tid] = beta[tid];
    }
    __syncthreads();

    const bf16x8* pw = (const bf16x8*)packW;
    bf16x8 w1[4], w2[8], w3[8], w4[8];
    #pragma unroll
    for (int f = 0; f < 4; ++f) w1[f] = pw[f * 64 + lane];
    #pragma unroll
    for (int f = 0; f < 8; ++f) w2[f] = pw[256 + f * 64 + lane];
    #pragma unroll
    for (int f = 0; f < 8; ++f) w3[f] = pw[768 + f * 64 + lane];
    #pragma unroll
    for (int f = 0; f < 8; ++f) w4[f] = pw[1280 + f * 64 + lane];

    ush* hb = &hbuf[wave][0];
    const int l15 = lane & 15, lg = lane >> 4;

    for (int s = 0; s < 2; ++s) {
        const int rowBase = blockIdx.x * 128 + wave * 32 + s * 16;

        const int rr = min(rowBase + l15, E - 1);
        const float4* xp = (const float4*)(x + (size_t)rr * IN_DIM + lg * 8);
        const float4 xa = xp[0], xb = xp[1];
        bf16x8 aL1;
        aL1[0] = (short)f2b(xa.x); aL1[1] = (short)f2b(xa.y);
        aL1[2] = (short)f2b(xa.z); aL1[3] = (short)f2b(xa.w);
        aL1[4] = (short)f2b(xb.x); aL1[5] = (short)f2b(xb.y);
        aL1[6] = (short)f2b(xb.z); aL1[7] = (short)f2b(xb.w);

        f32x4 acc[4];

        #pragma unroll
        for (int ct = 0; ct < 4; ++ct) {
            const float bv = sB[0 * HID + ct * 16 + l15];
            f32x4 c = {bv, bv, bv, bv};
            c = __builtin_amdgcn_mfma_f32_16x16x32_bf16(aL1, w1[ct], c, 0, 0, 0);
            acc[ct] = c;
        }

        #pragma unroll
        for (int ct = 0; ct < 4; ++ct)
            #pragma unroll
            for (int r = 0; r < 4; ++r) {
                float v = acc[ct][r]; v = v > 0.f ? v : 0.f;
                hb[(lg * 4 + r) * 72 + ct * 16 + l15] = f2b(v);
            }

        #define LAYER(WARR, BIDX, RELU_) do {                                   \
            const bf16x8 a0 = *(const bf16x8*)&hb[l15 * 72 + 0 * 32 + lg * 8];  \
            const bf16x8 a1 = *(const bf16x8*)&hb[l15 * 72 + 1 * 32 + lg * 8];  \
            _Pragma("unroll")                                                   \
            for (int ct = 0; ct < 4; ++ct) {                                    \
                const float bv = sB[(BIDX) * HID + ct * 16 + l15];              \
                f32x4 c = {bv, bv, bv, bv};                                     \
                c = __builtin_amdgcn_mfma_f32_16x16x32_bf16(a0, WARR[ct], c, 0, 0, 0);      \
                c = __builtin_amdgcn_mfma_f32_16x16x32_bf16(a1, WARR[4 + ct], c, 0, 0, 0);  \
                acc[ct] = c;                                                    \
            }                                                                   \
            if (RELU_) {                                                        \
                _Pragma("unroll")                                               \
                for (int ct = 0; ct < 4; ++ct)                                  \
                    _Pragma("unroll")                                           \
                    for (int r = 0; r < 4; ++r) {                               \
                        float v = acc[ct][r]; v = v > 0.f ? v : 0.f;            \
                        hb[(lg * 4 + r) * 72 + ct * 16 + l15] = f2b(v);         \
                    }                                                           \
            }                                                                   \
        } while (0)

        LAYER(w2, 1, 1);
        LAYER(w3, 2, 1);
        LAYER(w4, 3, 0);
        #undef LAYER

        float s1[4], s2[4];
        #pragma unroll
        for (int r = 0; r < 4; ++r) {
            float a = acc[0][r] + acc[1][r] + acc[2][r] + acc[3][r];
            float q = acc[0][r] * acc[0][r] + acc[1][r] * acc[1][r]
                    + acc[2][r] * acc[2][r] + acc[3][r] * acc[3][r];
            #pragma unroll
            for (int m = 1; m < 16; m <<= 1) {
                a += __shfl_xor(a, m, 64);
                q += __shfl_xor(q, m, 64);
            }
            s1[r] = a; s2[r] = q;
        }

        #pragma unroll
        for (int r = 0; r < 4; ++r) {
            const float mu = s1[r] * (1.0f / HID);
            const float varr = fmaxf(s2[r] * (1.0f / HID) - mu * mu, 0.f);
            const float inv = rsqrtf(varr + LN_EPS);
            const int row = rowBase + lg * 4 + r;
            if (row < E) {
                float* op = out_edge + (size_t)row * HID;
                #pragma unroll
                for (int ct = 0; ct < 4; ++ct) {
                    const float g = sB[4 * HID + ct * 16 + l15];
                    const float bt = sB[5 * HID + ct * 16 + l15];
                    op[ct * 16 + l15] = g * (acc[ct][r] - mu) * inv + bt;
                }
            }
        }
    }
}

// ---------------- fallback: VALU kernel with atomics (ws too small) ----------------
__global__ __launch_bounds__(256) void mlp_ln_scatter_fb(
    const float* __restrict__ x, const int* __restrict__ idx,
    const float* __restrict__ W1, const float* __restrict__ b1,
    const float* __restrict__ W2, const float* __restrict__ b2,
    const float* __restrict__ W3, const float* __restrict__ b3,
    const float* __restrict__ W4, const float* __restrict__ b4,
    const float* __restrict__ gamma, const float* __restrict__ beta,
    float* __restrict__ out_edge, float* __restrict__ node_acc, int E, int N)
{
    __shared__ float sW1[IN_DIM * HID];
    __shared__ float sW2[HID * HID];
    __shared__ float sW3[HID * HID];
    __shared__ float sW4[HID * HID];
    __shared__ float sB[6 * HID];
    const int tid = threadIdx.x;
    {
        const float4* W1v = (const float4*)W1;
        float4* s1 = (float4*)sW1;
        for (int i = tid; i < IN_DIM * HID / 4; i += 256) s1[i] = W1v[i];
        const float4* W2v = (const float4*)W2;
        const float4* W3v = (const float4*)W3;
        const float4* W4v = (const float4*)W4;
        float4* s2 = (float4*)sW2; float4* s3 = (float4*)sW3; float4* s4 = (float4*)sW4;
        for (int i = tid; i < HID * HID / 4; i += 256) { s2[i] = W2v[i]; s3[i] = W3v[i]; s4[i] = W4v[i]; }
        if (tid < HID) {
            sB[tid] = b1[tid]; sB[HID + tid] = b2[tid]; sB[2 * HID + tid] = b3[tid];
            sB[3 * HID + tid] = b4[tid]; sB[4 * HID + tid] = gamma[tid]; sB[5 * HID + tid] = beta[tid];
        }
    }
    __syncthreads();
    const int e = blockIdx.x * 256 + tid;
    if (e >= E) return;
    float h0[IN_DIM];
    {
        const float4* xv = (const float4*)(x + (size_t)e * IN_DIM);
        #pragma unroll
        for (int c = 0; c < 8; ++c) {
            const float4 v = xv[c];
            h0[c * 4 + 0] = v.x; h0[c * 4 + 1] = v.y; h0[c * 4 + 2] = v.z; h0[c * 4 + 3] = v.w;
        }
    }
    float a[HID], h[HID];
    #pragma unroll
    for (int j = 0; j < HID; ++j) a[j] = sB[j];
    #pragma unroll
    for (int k = 0; k < IN_DIM; ++k) {
        const float hk = h0[k];
        #pragma unroll
        for (int j = 0; j < HID; ++j) a[j] = fmaf(hk, sW1[k * HID + j], a[j]);
    }
    #pragma unroll
    for (int j = 0; j < HID; ++j) h[j] = a[j] > 0.f ? a[j] : 0.f;
    #pragma unroll
    for (int j = 0; j < HID; ++j) a[j] = sB[HID + j];
    #pragma unroll
    for (int k = 0; k < HID; ++k) {
        const float hk = h[k];
        #pragma unroll
        for (int j = 0; j < HID; ++j) a[j] = fmaf(hk, sW2[k * HID + j], a[j]);
    }
    #pragma unroll
    for (int j = 0; j < HID; ++j) h[j] = a[j] > 0.f ? a[j] : 0.f;
    #pragma unroll
    for (int j = 0; j < HID; ++j) a[j] = sB[2 * HID + j];
    #pragma unroll
    for (int k = 0; k < HID; ++k) {
        const float hk = h[k];
        #pragma unroll
        for (int j = 0; j < HID; ++j) a[j] = fmaf(hk, sW3[k * HID + j], a[j]);
    }
    #pragma unroll
    for (int j = 0; j < HID; ++j) h[j] = a[j] > 0.f ? a[j] : 0.f;
    #pragma unroll
    for (int j = 0; j < HID; ++j) a[j] = sB[3 * HID + j];
    #pragma unroll
    for (int k = 0; k < HID; ++k) {
        const float hk = h[k];
        #pragma unroll
        for (int j = 0; j < HID; ++j) a[j] = fmaf(hk, sW4[k * HID + j], a[j]);
    }
    float s = 0.f;
    #pragma unroll
    for (int j = 0; j < HID; ++j) s += a[j];
    const float mu = s * (1.0f / HID);
    float s2 = 0.f;
    #pragma unroll
    for (int j = 0; j < HID; ++j) { const float d = a[j] - mu; s2 += d * d; }
    const float inv = rsqrtf(s2 * (1.0f / HID) + LN_EPS);
    #pragma unroll
    for (int j = 0; j < HID; ++j)
        a[j] = sB[4 * HID + j] * ((a[j] - mu) * inv) + sB[5 * HID + j];
    {
        float4* oe = (float4*)(out_edge + (size_t)e * HID);
        #pragma unroll
        for (int c = 0; c < 16; ++c)
            oe[c] = make_float4(a[c * 4], a[c * 4 + 1], a[c * 4 + 2], a[c * 4 + 3]);
    }
    const bool idx64 = sniff_idx64(idx);
    int na, nb;
    if (idx64) { na = idx[4 * (size_t)e]; nb = idx[4 * (size_t)e + 2]; }
    else       { na = idx[2 * (size_t)e]; nb = idx[2 * (size_t)e + 1]; }
    na = min(max(na, 0), N - 1);
    nb = min(max(nb, 0), N - 1);
    float* pa = node_acc + (size_t)na * HID;
    float* pb = node_acc + (size_t)nb * HID;
    #pragma unroll
    for (int j = 0; j < HID; ++j) {
        unsafeAtomicAdd(pa + j, a[j]);
        unsafeAtomicAdd(pb + j, a[j]);
    }
}

extern "C" void kernel_launch(void* const* d_in, const int* in_sizes, int n_in,
                              void* d_out, int out_size, void* d_ws, size_t ws_size,
                              hipStream_t stream) {
    const float* x     = (const float*)d_in[0];
    const int*   idx   = (const int*)d_in[1];
    const float* W1    = (const float*)d_in[3];
    const float* b1    = (const float*)d_in[4];
    const float* W2    = (const float*)d_in[5];
    const float* b2    = (const float*)d_in[6];
    const float* W3    = (const float*)d_in[7];
    const float* b3    = (const float*)d_in[8];
    const float* W4    = (const float*)d_in[9];
    const float* b4    = (const float*)d_in[10];
    const float* gamma = (const float*)d_in[11];
    const float* beta  = (const float*)d_in[12];

    const int E = in_sizes[0] / IN_DIM;
    const int N = out_size / HID - E;
    const int NB = (N + (1 << BSH) - 1) >> BSH;   // 8-node buckets

    float* out_node = (float*)d_out;
    float* out_edge = out_node + (size_t)N * HID;

    // ws layout: pack(32KB) | bstart[NB] | bcur[NB] | nstart[N] | buf[2E]
    const size_t bstartOff = 32768;
    const size_t bcurOff   = bstartOff + (((size_t)NB * 4 + 255) & ~255ull);
    const size_t nstartOff = bcurOff + (((size_t)NB * 4 + 255) & ~255ull);
    const size_t bufOff    = nstartOff + (((size_t)N * 4 + 255) & ~255ull);
    const size_t need      = bufOff + (size_t)2 * E * sizeof(u32);

    if (ws_size >= need) {
        ush* pack   = (ush*)d_ws;
        int* bstart = (int*)((char*)d_ws + bstartOff);
        int* bcur   = (int*)((char*)d_ws + bcurOff);
        int* nstart = (int*)((char*)d_ws + nstartOff);
        u32* buf    = (u32*)((char*)d_ws + bufOff);

        pack_weights<<<(14336 + 255) / 256, 256, 0, stream>>>(W1, W2, W3, W4, pack);
        zero_i32<<<(NB + 255) / 256, 256, 0, stream>>>(bstart, NB);
        bucket_count<<<(2 * E + 255) / 256, 256, 0, stream>>>(idx, bstart, E, N);
        scan_excl2<<<1, 1024, 0, stream>>>(bstart, bcur, NB);
        append_pairs<<<(2 * E + 255) / 256, 256, 0, stream>>>(idx, bcur, buf, E, N);
        bucket_sort<<<(NB + 3) / 4, 256, 0, stream>>>(bstart, bcur, buf, nstart, NB, N);
        mlp_ln_mfma<<<(E + 127) / 128, 256, 0, stream>>>(
            x, pack, b1, b2, b3, b4, gamma, beta, out_edge, E);
        node_gather<<<(N * 64 + 255) / 256, 256, 0, stream>>>(
            nstart, bstart, bcur, buf, out_edge, out_node, N);
    } else {
        const int n16 = (int)(((size_t)N * HID * sizeof(float)) / 16);
        zero16<<<(n16 + 255) / 256, 256, 0, stream>>>((uint4*)out_node, n16);
        mlp_ln_scatter_fb<<<(E + 255) / 256, 256, 0, stream>>>(
            x, idx, W1, b1, W2, b2, W3, b3, W4, b4, gamma, beta,
            out_edge, out_node, E, N);
    }
}